// Round 1
// baseline (4474.080 us; speedup 1.0000x reference)
//
#include <hip/hip_runtime.h>
#include <hip/hip_bf16.h>
#include <hip/hip_cooperative_groups.h>
#include <type_traits>

#define T_ 256
#define B_ 128
#define DIN_ 512
#define H_ 1024
#define DOUT_ 512

typedef __attribute__((ext_vector_type(8))) short bf16x8;
typedef __attribute__((ext_vector_type(4))) short s16x4;
typedef __attribute__((ext_vector_type(4))) float f32x4;

__device__ inline short f2bf(float f) {
    return __builtin_bit_cast(short, __float2bfloat16(f));
}
__device__ inline float zload(const float* p) { return *p; }
__device__ inline float zload(const short* p) {
    unsigned u = ((unsigned)*(const unsigned short*)p) << 16;
    return __builtin_bit_cast(float, u);
}

// ---------------------------------------------------------------------------
// Generic GEMM: out[M][N] = A[M][K] * W[N][K]^T + b1 (+ b2), bf16 MFMA.
// 128x128 tile, 4 waves (2x2), each wave 64x64 (4x4 frags of 16x16x32).
// A and W are fp32; converted to bf16 during LDS staging (fragment layout).
// ---------------------------------------------------------------------------
template <typename OUT_T>
__global__ __launch_bounds__(256)
void gemm_bias(const float* __restrict__ A, const float* __restrict__ W,
               const float* __restrict__ b1, const float* __restrict__ b2,
               OUT_T* __restrict__ out, int M, int N, int K)
{
    __shared__ short lA[4096];   // [mt(8)][lane(64)][j(8)] bf16
    __shared__ short lB[4096];
    const int ntiles = N >> 7;
    const int bm = blockIdx.x / ntiles;
    const int bn = blockIdx.x % ntiles;
    const size_t m0 = (size_t)bm << 7;
    const size_t n0 = (size_t)bn << 7;
    const int tid = threadIdx.x;
    const int w = tid >> 6, l = tid & 63;
    const int wm = (w >> 1) << 6, wn = (w & 1) << 6;

    f32x4 acc[4][4] = {};
    float4 ra[4], rb[4];

    auto load_regs = [&](int k0) {
#pragma unroll
        for (int i = 0; i < 4; ++i) {
            int s = i * 256 + tid;
            int row = s >> 3, kq = s & 7;
            ra[i] = *(const float4*)(A + (m0 + row) * K + k0 + kq * 4);
            rb[i] = *(const float4*)(W + (n0 + row) * K + k0 + kq * 4);
        }
    };
    auto store_lds = [&]() {
#pragma unroll
        for (int i = 0; i < 4; ++i) {
            int s = i * 256 + tid;
            int row = s >> 3, kq = s & 7;
            // element (row, k=kq*4..+3) -> frag: lane=(row&15)|((k>>3)<<4), j=k&7
            int off = ((row >> 4) * 64 + ((row & 15) | ((kq >> 1) << 4))) * 8 + (kq & 1) * 4;
            s16x4 pa = { f2bf(ra[i].x), f2bf(ra[i].y), f2bf(ra[i].z), f2bf(ra[i].w) };
            s16x4 pb = { f2bf(rb[i].x), f2bf(rb[i].y), f2bf(rb[i].z), f2bf(rb[i].w) };
            *(s16x4*)&lA[off] = pa;
            *(s16x4*)&lB[off] = pb;
        }
    };

    load_regs(0);
    const int KI = K >> 5;
    for (int ki = 0; ki < KI; ++ki) {
        __syncthreads();            // previous iter's frag reads done
        store_lds();
        __syncthreads();
        if (ki + 1 < KI) load_regs((ki + 1) << 5);   // issue early: hides under MFMA
        bf16x8 aF[4], bF[4];
#pragma unroll
        for (int i = 0; i < 4; ++i) {
            aF[i] = *(const bf16x8*)&lA[(((wm >> 4) + i) * 64 + l) * 8];
            bF[i] = *(const bf16x8*)&lB[(((wn >> 4) + i) * 64 + l) * 8];
        }
#pragma unroll
        for (int i = 0; i < 4; ++i)
#pragma unroll
            for (int j = 0; j < 4; ++j)
                acc[i][j] = __builtin_amdgcn_mfma_f32_16x16x32_bf16(aF[i], bF[j], acc[i][j], 0, 0, 0);
    }

#pragma unroll
    for (int j = 0; j < 4; ++j) {
        const int col = (int)n0 + wn + j * 16 + (l & 15);
        float bb = b1[col];
        if (b2) bb += b2[col];
#pragma unroll
        for (int i = 0; i < 4; ++i) {
#pragma unroll
            for (int r = 0; r < 4; ++r) {
                int row = (int)m0 + wm + i * 16 + (l >> 4) * 4 + r;
                float v = acc[i][j][r] + bb;
                if constexpr (std::is_same<OUT_T, short>::value)
                    out[(size_t)row * N + col] = f2bf(v);
                else
                    out[(size_t)row * N + col] = v;
            }
        }
    }
}

// ---------------------------------------------------------------------------
// Recurrence: h_t = relu(zi_t + h_{t-1} @ Wh^T).  64 WGs x 256 thr.
// WG owns 16 output columns; its Wh slice lives in LDS (B-frag layout).
// h is double-buffered in global memory in A-fragment layout:
//   hbuf[buf][mt(8)][kk(32)][lane(64)][j(8)]  (bf16)
// so each wave A-operand load is one coalesced global_load_dwordx4.
// One grid.sync() per timestep.
// ---------------------------------------------------------------------------
template <typename ZT>
__global__ __launch_bounds__(256)
void rnn_rec(const ZT* __restrict__ zi, const float* __restrict__ Wh,
             float* __restrict__ hidden, short* __restrict__ hbuf)
{
    cooperative_groups::grid_group grid = cooperative_groups::this_grid();
    const int wg = blockIdx.x;          // 0..63
    const int o0 = wg << 4;             // 16 output columns
    const int tid = threadIdx.x, w = tid >> 6, l = tid & 63;

    __shared__ short lW[16384];         // [kk(32)][lane(64)][j(8)] bf16, 32KB
    for (int s = tid; s < 2048; s += 256) {
        int kk = s >> 6, ll = s & 63;
        int n = o0 + (ll & 15);
        int k = (kk << 5) + ((ll >> 4) << 3);
        const float4 f0 = *(const float4*)(Wh + (size_t)n * H_ + k);
        const float4 f1 = *(const float4*)(Wh + (size_t)n * H_ + k + 4);
        s16x4 p0 = { f2bf(f0.x), f2bf(f0.y), f2bf(f0.z), f2bf(f0.w) };
        s16x4 p1 = { f2bf(f1.x), f2bf(f1.y), f2bf(f1.z), f2bf(f1.w) };
        *(s16x4*)&lW[s * 8] = p0;
        *(s16x4*)&lW[s * 8 + 4] = p1;
    }
    __syncthreads();

    const int mt0 = w << 1, mt1 = mt0 + 1;   // 2 M-tiles (32 batch rows) per wave
    const int oc = o0 + (l & 15);
    const int bq = (l >> 4) << 2;
    const int lane_o = ((oc >> 3) & 3) << 4; // hfrag write lane bits from k=oc
    const int kk_o = oc >> 5;
    const int j_o = oc & 7;

    for (int t = 0; t < T_; ++t) {
        const size_t zb = (size_t)t * B_ * H_;
        // issue zi loads early; consumed only after the K-loop
        float z0[4], z1[4];
#pragma unroll
        for (int r = 0; r < 4; ++r) {
            z0[r] = zload(zi + zb + (size_t)((mt0 << 4) + bq + r) * H_ + oc);
            z1[r] = zload(zi + zb + (size_t)((mt1 << 4) + bq + r) * H_ + oc);
        }
        f32x4 acc0 = {}, acc1 = {};
        if (t > 0) {
            const short* hp = hbuf + ((t + 1) & 1) * (B_ * H_);
#pragma unroll 4
            for (int kk = 0; kk < 32; ++kk) {
                bf16x8 a0 = *(const bf16x8*)(hp + (((mt0 << 5) + kk) * 64 + l) * 8);
                bf16x8 a1 = *(const bf16x8*)(hp + (((mt1 << 5) + kk) * 64 + l) * 8);
                bf16x8 bw = *(const bf16x8*)&lW[((kk << 6) + l) * 8];
                acc0 = __builtin_amdgcn_mfma_f32_16x16x32_bf16(a0, bw, acc0, 0, 0, 0);
                acc1 = __builtin_amdgcn_mfma_f32_16x16x32_bf16(a1, bw, acc1, 0, 0, 0);
            }
        }
        short* hc = hbuf + (t & 1) * (B_ * H_);
#pragma unroll
        for (int r = 0; r < 4; ++r) {
            {
                float v = fmaxf(acc0[r] + z0[r], 0.f);
                int b = (mt0 << 4) + bq + r;
                hidden[zb + (size_t)b * H_ + oc] = v;
                hc[((mt0 * 32 + kk_o) * 64 + ((b & 15) | lane_o)) * 8 + j_o] = f2bf(v);
            }
            {
                float v = fmaxf(acc1[r] + z1[r], 0.f);
                int b = (mt1 << 4) + bq + r;
                hidden[zb + (size_t)b * H_ + oc] = v;
                hc[((mt1 * 32 + kk_o) * 64 + ((b & 15) | lane_o)) * 8 + j_o] = f2bf(v);
            }
        }
        grid.sync();
    }
}

__global__ __launch_bounds__(256)
void copy_k(const float4* __restrict__ s, float4* __restrict__ d)
{
    int i = blockIdx.x * 256 + threadIdx.x;
    d[i] = s[i];
}

extern "C" void kernel_launch(void* const* d_in, const int* in_sizes, int n_in,
                              void* d_out, int out_size, void* d_ws, size_t ws_size,
                              hipStream_t stream)
{
    const float* x  = (const float*)d_in[0];
    const float* Wi = (const float*)d_in[1];
    const float* bi = (const float*)d_in[2];
    const float* Wh = (const float*)d_in[3];
    const float* bh = (const float*)d_in[4];
    const float* Wo = (const float*)d_in[5];
    const float* bo = (const float*)d_in[6];

    float* hidden = (float*)d_out;                       // [T][B][H]
    float* hT     = hidden + (size_t)T_ * B_ * H_;       // [B][H]
    float* y      = hT + (size_t)B_ * H_;                // [T][B][O]

    const size_t ziF   = (size_t)T_ * B_ * H_ * sizeof(float);
    const size_t hbufB = (size_t)2 * B_ * H_ * sizeof(short);

    if (ws_size >= ziF + hbufB) {
        // Plan A: fp32 zi in workspace (better accuracy headroom)
        float* zi   = (float*)d_ws;
        short* hbuf = (short*)((char*)d_ws + ziF);
        gemm_bias<float><<<dim3(2048), dim3(256), 0, stream>>>(
            x, Wi, bi, bh, zi, T_ * B_, H_, DIN_);
        const float* zic = zi;
        void* args[4] = { &zic, &Wh, &hidden, &hbuf };
        auto kf = rnn_rec<float>;
        hipLaunchCooperativeKernel(reinterpret_cast<void*>(kf), dim3(64), dim3(256),
                                   args, 0, stream);
    } else {
        // Plan C: zi (bf16) lives in the y-section of d_out; h double-buffer in
        // the hT-section. Both are overwritten by later kernels in this launch.
        short* zi   = (short*)y;
        short* hbuf = (short*)hT;
        gemm_bias<short><<<dim3(2048), dim3(256), 0, stream>>>(
            x, Wi, bi, bh, zi, T_ * B_, H_, DIN_);
        const short* zic = zi;
        void* args[4] = { &zic, &Wh, &hidden, &hbuf };
        auto kf = rnn_rec<short>;
        hipLaunchCooperativeKernel(reinterpret_cast<void*>(kf), dim3(64), dim3(256),
                                   args, 0, stream);
    }

    // hT = hidden[T-1]  (also frees the hT-section from its hbuf role in Plan C)
    copy_k<<<dim3(128), dim3(256), 0, stream>>>(
        (const float4*)(hidden + (size_t)(T_ - 1) * B_ * H_), (float4*)hT);

    // y = hidden @ Wo^T + bo
    gemm_bias<float><<<dim3(1024), dim3(256), 0, stream>>>(
        hidden, Wo, bo, nullptr, y, T_ * B_, DOUT_, H_);
}

// Round 3
// 3059.026 us; speedup vs baseline: 1.4626x; 1.4626x over previous
//
#include <hip/hip_runtime.h>
#include <hip/hip_bf16.h>
#include <type_traits>

#define T_ 256
#define B_ 128
#define DIN_ 512
#define H_ 1024
#define DOUT_ 512

typedef __attribute__((ext_vector_type(8))) short bf16x8;
typedef __attribute__((ext_vector_type(4))) short s16x4;
typedef __attribute__((ext_vector_type(4))) float f32x4;
typedef __attribute__((ext_vector_type(2))) unsigned long long u64x2;
typedef unsigned long long u64;

__device__ unsigned g_flags[1024];   // 64 WGs x 16-uint stride; zeroed each launch

__device__ inline short f2bf(float f) {
    return __builtin_bit_cast(short, __float2bfloat16(f));
}
__device__ inline float4 zload4(const float* p) { return *(const float4*)p; }
__device__ inline float4 zload4(const short* p) {
    u64 u = *(const u64*)p;
    auto bf = [](unsigned x) { return __builtin_bit_cast(float, x << 16); };
    return make_float4(bf((unsigned)(u & 0xffff) ), bf((unsigned)((u >> 16) & 0xffff)),
                       bf((unsigned)((u >> 32) & 0xffff)), bf((unsigned)((u >> 48) & 0xffff)));
}
__device__ inline u64 pack4bf(float v0, float v1, float v2, float v3) {
    return (u64)(unsigned short)f2bf(v0)
         | ((u64)(unsigned short)f2bf(v1) << 16)
         | ((u64)(unsigned short)f2bf(v2) << 32)
         | ((u64)(unsigned short)f2bf(v3) << 48);
}

#define AT_LD64(p)    __hip_atomic_load((p), __ATOMIC_RELAXED, __HIP_MEMORY_SCOPE_AGENT)
#define AT_ST64(p, v) __hip_atomic_store((p), (v), __ATOMIC_RELAXED, __HIP_MEMORY_SCOPE_AGENT)

__global__ void zero_flags() { g_flags[blockIdx.x * 256 + threadIdx.x] = 0; }

// ---------------------------------------------------------------------------
// Generic GEMM: out[M][N] = A[M][K] * W[N][K]^T + b1 (+ b2), bf16 MFMA.
// (unchanged — validated in round 1)
// ---------------------------------------------------------------------------
template <typename OUT_T>
__global__ __launch_bounds__(256)
void gemm_bias(const float* __restrict__ A, const float* __restrict__ W,
               const float* __restrict__ b1, const float* __restrict__ b2,
               OUT_T* __restrict__ out, int M, int N, int K)
{
    __shared__ short lA[4096];
    __shared__ short lB[4096];
    const int ntiles = N >> 7;
    const int bm = blockIdx.x / ntiles;
    const int bn = blockIdx.x % ntiles;
    const size_t m0 = (size_t)bm << 7;
    const size_t n0 = (size_t)bn << 7;
    const int tid = threadIdx.x;
    const int w = tid >> 6, l = tid & 63;
    const int wm = (w >> 1) << 6, wn = (w & 1) << 6;

    f32x4 acc[4][4] = {};
    float4 ra[4], rb[4];

    auto load_regs = [&](int k0) {
#pragma unroll
        for (int i = 0; i < 4; ++i) {
            int s = i * 256 + tid;
            int row = s >> 3, kq = s & 7;
            ra[i] = *(const float4*)(A + (m0 + row) * K + k0 + kq * 4);
            rb[i] = *(const float4*)(W + (n0 + row) * K + k0 + kq * 4);
        }
    };
    auto store_lds = [&]() {
#pragma unroll
        for (int i = 0; i < 4; ++i) {
            int s = i * 256 + tid;
            int row = s >> 3, kq = s & 7;
            int off = ((row >> 4) * 64 + ((row & 15) | ((kq >> 1) << 4))) * 8 + (kq & 1) * 4;
            s16x4 pa = { f2bf(ra[i].x), f2bf(ra[i].y), f2bf(ra[i].z), f2bf(ra[i].w) };
            s16x4 pb = { f2bf(rb[i].x), f2bf(rb[i].y), f2bf(rb[i].z), f2bf(rb[i].w) };
            *(s16x4*)&lA[off] = pa;
            *(s16x4*)&lB[off] = pb;
        }
    };

    load_regs(0);
    const int KI = K >> 5;
    for (int ki = 0; ki < KI; ++ki) {
        __syncthreads();
        store_lds();
        __syncthreads();
        if (ki + 1 < KI) load_regs((ki + 1) << 5);
        bf16x8 aF[4], bF[4];
#pragma unroll
        for (int i = 0; i < 4; ++i) {
            aF[i] = *(const bf16x8*)&lA[(((wm >> 4) + i) * 64 + l) * 8];
            bF[i] = *(const bf16x8*)&lB[(((wn >> 4) + i) * 64 + l) * 8];
        }
#pragma unroll
        for (int i = 0; i < 4; ++i)
#pragma unroll
            for (int j = 0; j < 4; ++j)
                acc[i][j] = __builtin_amdgcn_mfma_f32_16x16x32_bf16(aF[i], bF[j], acc[i][j], 0, 0, 0);
    }

#pragma unroll
    for (int j = 0; j < 4; ++j) {
        const int col = (int)n0 + wn + j * 16 + (l & 15);
        float bb = b1[col];
        if (b2) bb += b2[col];
#pragma unroll
        for (int i = 0; i < 4; ++i) {
#pragma unroll
            for (int r = 0; r < 4; ++r) {
                int row = (int)m0 + wm + i * 16 + (l >> 4) * 4 + r;
                float v = acc[i][j][r] + bb;
                if constexpr (std::is_same<OUT_T, short>::value)
                    out[(size_t)row * N + col] = f2bf(v);
                else
                    out[(size_t)row * N + col] = v;
            }
        }
    }
}

// ---------------------------------------------------------------------------
// Recurrence v3: batch-independent partition, plain launch, device-global
// flags, release/acquire message passing.
//   8 batch-groups (16 rows) x 8 col-group WGs (128 cols), 256 thr.
//   Wave = 32 output cols; Wh slice resident in 256 VGPRs (A-frag layout).
//   Swapped MFMA: acc[oc, b] += Wh_frag * h_frag.
//   h exchanged via LLC: hbuf[buf][bg][kk][lane][j] bf16, relaxed-agent (sc1)
//   8B atomic ld/st. Barrier: __syncthreads -> tid0 RELEASE-store flag ->
//   wave0 relaxed poll + ACQUIRE fence -> __syncthreads.
// ---------------------------------------------------------------------------
template <typename ZT>
__global__ __launch_bounds__(256, 1)
void rnn_rec3(const ZT* __restrict__ zi, const float* __restrict__ Wh,
              float* __restrict__ hidden, unsigned short* __restrict__ hbuf)
{
    const int wg = blockIdx.x;           // 0..63
    const int bg = wg >> 3, cg = wg & 7;
    const int tid = threadIdx.x, w = tid >> 6, l = tid & 63;
    const int b = l & 15, hi = l >> 4;
    const int ocw = cg * 128 + w * 32;   // wave's first output column

    // ---- Wh -> registers (A-frag: oc row = l&15, k = (l>>4)*8 + j) ----
    bf16x8 wh[32][2];
#pragma unroll
    for (int kk = 0; kk < 32; ++kk) {
#pragma unroll
        for (int m = 0; m < 2; ++m) {
            const float* wp = Wh + (size_t)(ocw + m * 16 + b) * H_ + kk * 32 + hi * 8;
            float4 a = *(const float4*)wp;
            float4 c = *(const float4*)(wp + 4);
            bf16x8 v = { f2bf(a.x), f2bf(a.y), f2bf(a.z), f2bf(a.w),
                         f2bf(c.x), f2bf(c.y), f2bf(c.z), f2bf(c.w) };
            wh[kk][m] = v;
        }
    }

    float4 z[2];
#pragma unroll
    for (int m = 0; m < 2; ++m)
        z[m] = zload4(zi + ((size_t)bg * 16 + b) * H_ + ocw + m * 16 + hi * 4);

#pragma unroll 1
    for (int t = 0; t < T_; ++t) {
        const size_t zb = (size_t)t * B_ * H_;
        f32x4 acc[2][2] = {};     // [m][chain]
        if (t > 0) {
            const u64* hp = (const u64*)hbuf + (size_t)(((t + 1) & 1) * 8 + bg) * 4096;
#pragma unroll
            for (int kk = 0; kk < 32; ++kk) {
                u64 h0 = AT_LD64(hp + kk * 128 + l * 2);
                u64 h1 = AT_LD64(hp + kk * 128 + l * 2 + 1);
                u64x2 hv; hv.x = h0; hv.y = h1;
                bf16x8 hbf = __builtin_bit_cast(bf16x8, hv);
                acc[0][kk & 1] = __builtin_amdgcn_mfma_f32_16x16x32_bf16(wh[kk][0], hbf, acc[0][kk & 1], 0, 0, 0);
                acc[1][kk & 1] = __builtin_amdgcn_mfma_f32_16x16x32_bf16(wh[kk][1], hbf, acc[1][kk & 1], 0, 0, 0);
            }
        }
        // ---- epilogue: relu(acc + zi) -> hidden (plain) + hbuf (sc1) ----
        unsigned short* hwS = hbuf + (size_t)((t & 1) * 8 + bg) * 16384;
#pragma unroll
        for (int m = 0; m < 2; ++m) {
            const int f0 = ocw + m * 16 + hi * 4;
            float v0 = fmaxf(acc[m][0][0] + acc[m][1][0] + z[m].x, 0.f);
            float v1 = fmaxf(acc[m][0][1] + acc[m][1][1] + z[m].y, 0.f);
            float v2 = fmaxf(acc[m][0][2] + acc[m][1][2] + z[m].z, 0.f);
            float v3 = fmaxf(acc[m][0][3] + acc[m][1][3] + z[m].w, 0.f);
            *(float4*)(hidden + (zb + (size_t)(bg * 16 + b) * H_) + f0) =
                make_float4(v0, v1, v2, v3);
            const int kk2 = f0 >> 5, j0 = f0 & 7;
            const int lane2 = b | (((f0 >> 3) & 3) << 4);
            AT_ST64((u64*)(hwS + (kk2 * 64 + lane2) * 8 + j0), pack4bf(v0, v1, v2, v3));
        }

        __syncthreads();                      // intra-WG: all stores issued+drained
        if (tid == 0)
            __hip_atomic_store(&g_flags[wg * 16], (unsigned)(t + 1),
                               __ATOMIC_RELEASE, __HIP_MEMORY_SCOPE_AGENT);

        if (t + 1 < T_) {                     // prefetch zi(t+1) under the barrier
#pragma unroll
            for (int m = 0; m < 2; ++m)
                z[m] = zload4(zi + ((size_t)(t + 1) * B_ + bg * 16 + b) * H_ + ocw + m * 16 + hi * 4);
        }
        if (w == 0) {                         // wave 0 polls all 8 flags of this bg
            const unsigned tgt = (unsigned)(t + 1);
            const unsigned* fp = &g_flags[(bg * 8 + (l & 7)) * 16];
            unsigned v;
            do {
                v = __hip_atomic_load(fp, __ATOMIC_RELAXED, __HIP_MEMORY_SCOPE_AGENT);
            } while (!__all((int)(v >= tgt)));
            __builtin_amdgcn_fence(__ATOMIC_ACQUIRE, "agent");
        }
        __syncthreads();
    }
}

__global__ __launch_bounds__(256)
void copy_k(const float4* __restrict__ s, float4* __restrict__ d)
{
    int i = blockIdx.x * 256 + threadIdx.x;
    d[i] = s[i];
}

extern "C" void kernel_launch(void* const* d_in, const int* in_sizes, int n_in,
                              void* d_out, int out_size, void* d_ws, size_t ws_size,
                              hipStream_t stream)
{
    const float* x  = (const float*)d_in[0];
    const float* Wi = (const float*)d_in[1];
    const float* bi = (const float*)d_in[2];
    const float* Wh = (const float*)d_in[3];
    const float* bh = (const float*)d_in[4];
    const float* Wo = (const float*)d_in[5];
    const float* bo = (const float*)d_in[6];

    float* hidden = (float*)d_out;                       // [T][B][H]
    float* hT     = hidden + (size_t)T_ * B_ * H_;       // [B][H]
    float* y      = hT + (size_t)B_ * H_;                // [T][B][O]

    const size_t HBUF_B = (size_t)2 * B_ * H_ * sizeof(short);   // 512 KB
    const size_t ZI_B   = (size_t)T_ * B_ * H_ * sizeof(float);  // 128 MB

    zero_flags<<<dim3(4), dim3(256), 0, stream>>>();

    if (ws_size >= HBUF_B + ZI_B) {
        // Plan A: fp32 zi + hbuf in workspace
        unsigned short* hbuf = (unsigned short*)d_ws;
        float* zi = (float*)((char*)d_ws + HBUF_B);
        gemm_bias<float><<<dim3(2048), dim3(256), 0, stream>>>(
            x, Wi, bi, bh, zi, T_ * B_, H_, DIN_);
        rnn_rec3<float><<<dim3(64), dim3(256), 0, stream>>>(zi, Wh, hidden, hbuf);
    } else {
        // Plan C: zi (bf16) in y-section; hbuf in hT-section. No d_ws use.
        short* zi = (short*)y;
        unsigned short* hbuf = (unsigned short*)hT;
        gemm_bias<short><<<dim3(2048), dim3(256), 0, stream>>>(
            x, Wi, bi, bh, zi, T_ * B_, H_, DIN_);
        rnn_rec3<short><<<dim3(64), dim3(256), 0, stream>>>(zi, Wh, hidden, hbuf);
    }

    // hT = hidden[T-1]
    copy_k<<<dim3(128), dim3(256), 0, stream>>>(
        (const float4*)(hidden + (size_t)(T_ - 1) * B_ * H_), (float4*)hT);

    // y = hidden @ Wo^T + bo
    gemm_bias<float><<<dim3(1024), dim3(256), 0, stream>>>(
        hidden, Wo, bo, nullptr, y, T_ * B_, DOUT_, H_);
}

// Round 4
// 2508.378 us; speedup vs baseline: 1.7837x; 1.2195x over previous
//
#include <hip/hip_runtime.h>
#include <hip/hip_bf16.h>
#include <type_traits>

#define T_ 256
#define B_ 128
#define DIN_ 512
#define H_ 1024
#define DOUT_ 512

typedef __attribute__((ext_vector_type(8))) short bf16x8;
typedef __attribute__((ext_vector_type(4))) short s16x4;
typedef __attribute__((ext_vector_type(4))) float f32x4;
typedef __attribute__((ext_vector_type(2))) unsigned long long u64x2;
typedef unsigned long long u64;

__device__ unsigned g_flags[1024];   // 64 WGs x 16-uint stride; zeroed each launch

__device__ inline short f2bf(float f) {
    return __builtin_bit_cast(short, __float2bfloat16(f));
}
__device__ inline float4 zload4(const float* p) { return *(const float4*)p; }
__device__ inline float4 zload4(const short* p) {
    u64 u = *(const u64*)p;
    auto bf = [](unsigned x) { return __builtin_bit_cast(float, x << 16); };
    return make_float4(bf((unsigned)(u & 0xffff) ), bf((unsigned)((u >> 16) & 0xffff)),
                       bf((unsigned)((u >> 32) & 0xffff)), bf((unsigned)((u >> 48) & 0xffff)));
}
__device__ inline u64 pack4bf(float v0, float v1, float v2, float v3) {
    return (u64)(unsigned short)f2bf(v0)
         | ((u64)(unsigned short)f2bf(v1) << 16)
         | ((u64)(unsigned short)f2bf(v2) << 32)
         | ((u64)(unsigned short)f2bf(v3) << 48);
}

// All cross-WG traffic is relaxed agent-scope (sc1, LLC-homed). Ordering:
// producer __syncthreads drains vmcnt(0) (data ack'd at LLC) before tid0's
// flag store; consumer poll->barrier->loads. NO release/acquire: on gfx950
// those lower to buffer_wbl2/buffer_inv (full L2 writeback/invalidate) per
// WG per step -- measured round 3 at ~10.5 us/step of pure cache maintenance.
#define AT_LD64(p)    __hip_atomic_load((p), __ATOMIC_RELAXED, __HIP_MEMORY_SCOPE_AGENT)
#define AT_ST64(p, v) __hip_atomic_store((p), (v), __ATOMIC_RELAXED, __HIP_MEMORY_SCOPE_AGENT)
#define AT_LD32(p)    __hip_atomic_load((p), __ATOMIC_RELAXED, __HIP_MEMORY_SCOPE_AGENT)
#define AT_ST32(p, v) __hip_atomic_store((p), (v), __ATOMIC_RELAXED, __HIP_MEMORY_SCOPE_AGENT)

__global__ void zero_flags() { g_flags[blockIdx.x * 256 + threadIdx.x] = 0; }

// ---------------------------------------------------------------------------
// Generic GEMM: out[M][N] = A[M][K] * W[N][K]^T + b1 (+ b2), bf16 MFMA.
// (unchanged -- validated rounds 1/3)
// ---------------------------------------------------------------------------
template <typename OUT_T>
__global__ __launch_bounds__(256)
void gemm_bias(const float* __restrict__ A, const float* __restrict__ W,
               const float* __restrict__ b1, const float* __restrict__ b2,
               OUT_T* __restrict__ out, int M, int N, int K)
{
    __shared__ short lA[4096];
    __shared__ short lB[4096];
    const int ntiles = N >> 7;
    const int bm = blockIdx.x / ntiles;
    const int bn = blockIdx.x % ntiles;
    const size_t m0 = (size_t)bm << 7;
    const size_t n0 = (size_t)bn << 7;
    const int tid = threadIdx.x;
    const int w = tid >> 6, l = tid & 63;
    const int wm = (w >> 1) << 6, wn = (w & 1) << 6;

    f32x4 acc[4][4] = {};
    float4 ra[4], rb[4];

    auto load_regs = [&](int k0) {
#pragma unroll
        for (int i = 0; i < 4; ++i) {
            int s = i * 256 + tid;
            int row = s >> 3, kq = s & 7;
            ra[i] = *(const float4*)(A + (m0 + row) * K + k0 + kq * 4);
            rb[i] = *(const float4*)(W + (n0 + row) * K + k0 + kq * 4);
        }
    };
    auto store_lds = [&]() {
#pragma unroll
        for (int i = 0; i < 4; ++i) {
            int s = i * 256 + tid;
            int row = s >> 3, kq = s & 7;
            int off = ((row >> 4) * 64 + ((row & 15) | ((kq >> 1) << 4))) * 8 + (kq & 1) * 4;
            s16x4 pa = { f2bf(ra[i].x), f2bf(ra[i].y), f2bf(ra[i].z), f2bf(ra[i].w) };
            s16x4 pb = { f2bf(rb[i].x), f2bf(rb[i].y), f2bf(rb[i].z), f2bf(rb[i].w) };
            *(s16x4*)&lA[off] = pa;
            *(s16x4*)&lB[off] = pb;
        }
    };

    load_regs(0);
    const int KI = K >> 5;
    for (int ki = 0; ki < KI; ++ki) {
        __syncthreads();
        store_lds();
        __syncthreads();
        if (ki + 1 < KI) load_regs((ki + 1) << 5);
        bf16x8 aF[4], bF[4];
#pragma unroll
        for (int i = 0; i < 4; ++i) {
            aF[i] = *(const bf16x8*)&lA[(((wm >> 4) + i) * 64 + l) * 8];
            bF[i] = *(const bf16x8*)&lB[(((wn >> 4) + i) * 64 + l) * 8];
        }
#pragma unroll
        for (int i = 0; i < 4; ++i)
#pragma unroll
            for (int j = 0; j < 4; ++j)
                acc[i][j] = __builtin_amdgcn_mfma_f32_16x16x32_bf16(aF[i], bF[j], acc[i][j], 0, 0, 0);
    }

#pragma unroll
    for (int j = 0; j < 4; ++j) {
        const int col = (int)n0 + wn + j * 16 + (l & 15);
        float bb = b1[col];
        if (b2) bb += b2[col];
#pragma unroll
        for (int i = 0; i < 4; ++i) {
#pragma unroll
            for (int r = 0; r < 4; ++r) {
                int row = (int)m0 + wm + i * 16 + (l >> 4) * 4 + r;
                float v = acc[i][j][r] + bb;
                if constexpr (std::is_same<OUT_T, short>::value)
                    out[(size_t)row * N + col] = f2bf(v);
                else
                    out[(size_t)row * N + col] = v;
            }
        }
    }
}

// ---------------------------------------------------------------------------
// Recurrence v4 = v3 with pure-relaxed flag protocol (no wbl2/inv).
//   8 batch-groups (16 rows) x 8 col-group WGs (128 cols), 256 thr.
//   Wave = 32 output cols; Wh slice in VGPRs (A-frag). Swapped MFMA.
//   h via LLC: hbuf[buf][bg][kk][lane][j] bf16, relaxed sc1 8B atomics.
//   Barrier: __syncthreads (vmcnt0 drain) -> tid0 relaxed flag store ->
//   wave0 relaxed poll -> __syncthreads.
// ---------------------------------------------------------------------------
template <typename ZT>
__global__ __launch_bounds__(256, 1)
void rnn_rec4(const ZT* __restrict__ zi, const float* __restrict__ Wh,
              float* __restrict__ hidden, unsigned short* __restrict__ hbuf)
{
    const int wg = blockIdx.x;           // 0..63
    const int bg = wg >> 3, cg = wg & 7;
    const int tid = threadIdx.x, w = tid >> 6, l = tid & 63;
    const int b = l & 15, hi = l >> 4;
    const int ocw = cg * 128 + w * 32;   // wave's first output column

    // ---- Wh -> registers (A-frag: oc row = l&15, k = (l>>4)*8 + j) ----
    bf16x8 wh[32][2];
#pragma unroll
    for (int kk = 0; kk < 32; ++kk) {
#pragma unroll
        for (int m = 0; m < 2; ++m) {
            const float* wp = Wh + (size_t)(ocw + m * 16 + b) * H_ + kk * 32 + hi * 8;
            float4 a = *(const float4*)wp;
            float4 c = *(const float4*)(wp + 4);
            bf16x8 v = { f2bf(a.x), f2bf(a.y), f2bf(a.z), f2bf(a.w),
                         f2bf(c.x), f2bf(c.y), f2bf(c.z), f2bf(c.w) };
            wh[kk][m] = v;
        }
    }

    float4 z[2];
#pragma unroll
    for (int m = 0; m < 2; ++m)
        z[m] = zload4(zi + ((size_t)bg * 16 + b) * H_ + ocw + m * 16 + hi * 4);

#pragma unroll 1
    for (int t = 0; t < T_; ++t) {
        const size_t zb = (size_t)t * B_ * H_;
        f32x4 acc[2][2] = {};     // [m][chain]
        if (t > 0) {
            const u64* hp = (const u64*)hbuf + (size_t)(((t + 1) & 1) * 8 + bg) * 4096;
#pragma unroll
            for (int kk = 0; kk < 32; ++kk) {
                u64 h0 = AT_LD64(hp + kk * 128 + l * 2);
                u64 h1 = AT_LD64(hp + kk * 128 + l * 2 + 1);
                u64x2 hv; hv.x = h0; hv.y = h1;
                bf16x8 hbf = __builtin_bit_cast(bf16x8, hv);
                acc[0][kk & 1] = __builtin_amdgcn_mfma_f32_16x16x32_bf16(wh[kk][0], hbf, acc[0][kk & 1], 0, 0, 0);
                acc[1][kk & 1] = __builtin_amdgcn_mfma_f32_16x16x32_bf16(wh[kk][1], hbf, acc[1][kk & 1], 0, 0, 0);
            }
        }
        // ---- epilogue: relu(acc + zi) -> hidden (plain) + hbuf (sc1) ----
        unsigned short* hwS = hbuf + (size_t)((t & 1) * 8 + bg) * 16384;
#pragma unroll
        for (int m = 0; m < 2; ++m) {
            const int f0 = ocw + m * 16 + hi * 4;
            float v0 = fmaxf(acc[m][0][0] + acc[m][1][0] + z[m].x, 0.f);
            float v1 = fmaxf(acc[m][0][1] + acc[m][1][1] + z[m].y, 0.f);
            float v2 = fmaxf(acc[m][0][2] + acc[m][1][2] + z[m].z, 0.f);
            float v3 = fmaxf(acc[m][0][3] + acc[m][1][3] + z[m].w, 0.f);
            *(float4*)(hidden + (zb + (size_t)(bg * 16 + b) * H_) + f0) =
                make_float4(v0, v1, v2, v3);
            const int kk2 = f0 >> 5, j0 = f0 & 7;
            const int lane2 = b | (((f0 >> 3) & 3) << 4);
            AT_ST64((u64*)(hwS + (kk2 * 64 + lane2) * 8 + j0), pack4bf(v0, v1, v2, v3));
        }

        __syncthreads();                      // vmcnt(0): all stores ack'd at LLC
        if (tid == 0)
            AT_ST32(&g_flags[wg * 16], (unsigned)(t + 1));   // relaxed publish

        if (t + 1 < T_) {                     // prefetch zi(t+1) under the barrier
#pragma unroll
            for (int m = 0; m < 2; ++m)
                z[m] = zload4(zi + ((size_t)(t + 1) * B_ + bg * 16 + b) * H_ + ocw + m * 16 + hi * 4);
        }
        if (w == 0) {                         // wave 0 polls all 8 flags of this bg
            const unsigned tgt = (unsigned)(t + 1);
            const unsigned* fp = &g_flags[(bg * 8 + (l & 7)) * 16];
            unsigned v;
            do {
                v = AT_LD32(fp);
            } while (!__all((int)(v >= tgt)));
        }
        __syncthreads();
    }
}

__global__ __launch_bounds__(256)
void copy_k(const float4* __restrict__ s, float4* __restrict__ d)
{
    int i = blockIdx.x * 256 + threadIdx.x;
    d[i] = s[i];
}

extern "C" void kernel_launch(void* const* d_in, const int* in_sizes, int n_in,
                              void* d_out, int out_size, void* d_ws, size_t ws_size,
                              hipStream_t stream)
{
    const float* x  = (const float*)d_in[0];
    const float* Wi = (const float*)d_in[1];
    const float* bi = (const float*)d_in[2];
    const float* Wh = (const float*)d_in[3];
    const float* bh = (const float*)d_in[4];
    const float* Wo = (const float*)d_in[5];
    const float* bo = (const float*)d_in[6];

    float* hidden = (float*)d_out;                       // [T][B][H]
    float* hT     = hidden + (size_t)T_ * B_ * H_;       // [B][H]
    float* y      = hT + (size_t)B_ * H_;                // [T][B][O]

    const size_t HBUF_B = (size_t)2 * B_ * H_ * sizeof(short);   // 512 KB
    const size_t ZI_B   = (size_t)T_ * B_ * H_ * sizeof(short);  // 64 MB (bf16)

    zero_flags<<<dim3(4), dim3(256), 0, stream>>>();

    short* zi;
    unsigned short* hbuf;
    if (ws_size >= HBUF_B + ZI_B) {
        hbuf = (unsigned short*)d_ws;
        zi   = (short*)((char*)d_ws + HBUF_B);
    } else {
        // zi (bf16) in y-section; hbuf in hT-section (both overwritten later)
        zi   = (short*)y;
        hbuf = (unsigned short*)hT;
    }

    gemm_bias<short><<<dim3(2048), dim3(256), 0, stream>>>(
        x, Wi, bi, bh, zi, T_ * B_, H_, DIN_);
    rnn_rec4<short><<<dim3(64), dim3(256), 0, stream>>>(zi, Wh, hidden, hbuf);

    // hT = hidden[T-1]
    copy_k<<<dim3(128), dim3(256), 0, stream>>>(
        (const float4*)(hidden + (size_t)(T_ - 1) * B_ * H_), (float4*)hT);

    // y = hidden @ Wo^T + bo
    gemm_bias<float><<<dim3(1024), dim3(256), 0, stream>>>(
        hidden, Wo, bo, nullptr, y, T_ * B_, DOUT_, H_);
}

// Round 6
// 846.787 us; speedup vs baseline: 5.2836x; 2.9622x over previous
//
#include <hip/hip_runtime.h>
#include <hip/hip_bf16.h>
#include <type_traits>

#define T_ 256
#define B_ 128
#define DIN_ 512
#define H_ 1024
#define DOUT_ 512

typedef __attribute__((ext_vector_type(8))) short bf16x8;
typedef __attribute__((ext_vector_type(4))) short s16x4;
typedef __attribute__((ext_vector_type(4))) float f32x4;
typedef unsigned long long u64;

__device__ unsigned g_flags[2048];   // 128 WGs x 16-uint stride; zeroed each launch

__device__ inline short f2bf(float f) {
    return __builtin_bit_cast(short, __float2bfloat16(f));
}
__device__ inline float4 zload4(const short* p) {
    u64 u = *(const u64*)p;
    auto bf = [](unsigned x) { return __builtin_bit_cast(float, x << 16); };
    return make_float4(bf((unsigned)(u & 0xffff) ), bf((unsigned)((u >> 16) & 0xffff)),
                       bf((unsigned)((u >> 32) & 0xffff)), bf((unsigned)((u >> 48) & 0xffff)));
}
__device__ inline u64 pack4bf(float v0, float v1, float v2, float v3) {
    return (u64)(unsigned short)f2bf(v0)
         | ((u64)(unsigned short)f2bf(v1) << 16)
         | ((u64)(unsigned short)f2bf(v2) << 32)
         | ((u64)(unsigned short)f2bf(v3) << 48);
}

// Cross-WG protocol (round-6 hardening):
//   PRODUCER data (hbuf) and flag publishes are atomic EXCHANGES (RMW).
//   A relaxed sc1 STORE may be ack'd by an XCD-edge write buffer that drains
//   to the LLC out of order -> flag could become visible before data (round-5
//   post-timing divergence, hot-replay only). An RMW must EXECUTE at the LLC,
//   so vmcnt ack == LLC arrival; __syncthreads' vmcnt(0) drain then strictly
//   orders data-at-LLC before the flag publish. Consumer side (relaxed sc1
//   loads read the LLC) validated empirically in rounds 3/4.
#define AT_LD64(p)     __hip_atomic_load((p), __ATOMIC_RELAXED, __HIP_MEMORY_SCOPE_AGENT)
#define AT_SWP64(p, v) (void)__hip_atomic_exchange((p), (v), __ATOMIC_RELAXED, __HIP_MEMORY_SCOPE_AGENT)
#define AT_LD32(p)     __hip_atomic_load((p), __ATOMIC_RELAXED, __HIP_MEMORY_SCOPE_AGENT)
#define AT_SWP32(p, v) (void)__hip_atomic_exchange((p), (v), __ATOMIC_RELAXED, __HIP_MEMORY_SCOPE_AGENT)

__global__ void zero_flags() { g_flags[blockIdx.x * 256 + threadIdx.x] = 0; }

// ---------------------------------------------------------------------------
// Generic GEMM: out[M][N] = A[M][K] * W[N][K]^T + b1 (+ b2), bf16 MFMA.
// (unchanged -- validated rounds 1/3/4/5)
// ---------------------------------------------------------------------------
template <typename OUT_T>
__global__ __launch_bounds__(256)
void gemm_bias(const float* __restrict__ A, const float* __restrict__ W,
               const float* __restrict__ b1, const float* __restrict__ b2,
               OUT_T* __restrict__ out, int M, int N, int K)
{
    __shared__ short lA[4096];
    __shared__ short lB[4096];
    const int ntiles = N >> 7;
    const int bm = blockIdx.x / ntiles;
    const int bn = blockIdx.x % ntiles;
    const size_t m0 = (size_t)bm << 7;
    const size_t n0 = (size_t)bn << 7;
    const int tid = threadIdx.x;
    const int w = tid >> 6, l = tid & 63;
    const int wm = (w >> 1) << 6, wn = (w & 1) << 6;

    f32x4 acc[4][4] = {};
    float4 ra[4], rb[4];

    auto load_regs = [&](int k0) {
#pragma unroll
        for (int i = 0; i < 4; ++i) {
            int s = i * 256 + tid;
            int row = s >> 3, kq = s & 7;
            ra[i] = *(const float4*)(A + (m0 + row) * K + k0 + kq * 4);
            rb[i] = *(const float4*)(W + (n0 + row) * K + k0 + kq * 4);
        }
    };
    auto store_lds = [&]() {
#pragma unroll
        for (int i = 0; i < 4; ++i) {
            int s = i * 256 + tid;
            int row = s >> 3, kq = s & 7;
            int off = ((row >> 4) * 64 + ((row & 15) | ((kq >> 1) << 4))) * 8 + (kq & 1) * 4;
            s16x4 pa = { f2bf(ra[i].x), f2bf(ra[i].y), f2bf(ra[i].z), f2bf(ra[i].w) };
            s16x4 pb = { f2bf(rb[i].x), f2bf(rb[i].y), f2bf(rb[i].z), f2bf(rb[i].w) };
            *(s16x4*)&lA[off] = pa;
            *(s16x4*)&lB[off] = pb;
        }
    };

    load_regs(0);
    const int KI = K >> 5;
    for (int ki = 0; ki < KI; ++ki) {
        __syncthreads();
        store_lds();
        __syncthreads();
        if (ki + 1 < KI) load_regs((ki + 1) << 5);
        bf16x8 aF[4], bF[4];
#pragma unroll
        for (int i = 0; i < 4; ++i) {
            aF[i] = *(const bf16x8*)&lA[(((wm >> 4) + i) * 64 + l) * 8];
            bF[i] = *(const bf16x8*)&lB[(((wn >> 4) + i) * 64 + l) * 8];
        }
#pragma unroll
        for (int i = 0; i < 4; ++i)
#pragma unroll
            for (int j = 0; j < 4; ++j)
                acc[i][j] = __builtin_amdgcn_mfma_f32_16x16x32_bf16(aF[i], bF[j], acc[i][j], 0, 0, 0);
    }

#pragma unroll
    for (int j = 0; j < 4; ++j) {
        const int col = (int)n0 + wn + j * 16 + (l & 15);
        float bb = b1[col];
        if (b2) bb += b2[col];
#pragma unroll
        for (int i = 0; i < 4; ++i) {
#pragma unroll
            for (int r = 0; r < 4; ++r) {
                int row = (int)m0 + wm + i * 16 + (l >> 4) * 4 + r;
                float v = acc[i][j][r] + bb;
                if constexpr (std::is_same<OUT_T, short>::value)
                    out[(size_t)row * N + col] = f2bf(v);
                else
                    out[(size_t)row * N + col] = v;
            }
        }
    }
}

// ---------------------------------------------------------------------------
// Recurrence v6 = v5 structure + RMW-hardened producer path.
//   128 WGs = 8 bg (16 batch rows) x 16 cg (64 cols), 256 thr (4 waves).
//   Wave owns 16 cols: wh[32] = 128 VGPRs (A-frag), no spill.
//   Per step: stage bg's h(t-1) (32 KB, B-frag) LLC->LDS (16x8B/thread),
//   K-loop = ds_read_b128 + MFMA (2 chains). hbuf writes + flag = atomic
//   exchange (executes at LLC). Poll: relaxed sc1 loads (validated r3/r4).
// ---------------------------------------------------------------------------
__global__ __launch_bounds__(256, 1)
void rnn_rec6(const short* __restrict__ zi, const float* __restrict__ Wh,
              float* __restrict__ hidden, unsigned short* __restrict__ hbuf)
{
    const int wg = blockIdx.x;           // 0..127
    const int bg = wg >> 4, cg = wg & 15;
    const int tid = threadIdx.x, w = tid >> 6, l = tid & 63;
    const int b = l & 15, hi = l >> 4;
    const int ocw = cg * 64 + w * 16;    // wave's 16 output columns

    __shared__ u64 lds_h[4096];          // 32 KB: bg's h tile, B-frag layout

    // ---- Wh -> registers (A-frag: oc = ocw + (l&15), k = kk*32 + hi*8 + j) ----
    bf16x8 wh[32];
#pragma unroll
    for (int kk = 0; kk < 32; ++kk) {
        const float* wp = Wh + (size_t)(ocw + b) * H_ + kk * 32 + hi * 8;
        float4 a = *(const float4*)wp;
        float4 c = *(const float4*)(wp + 4);
        bf16x8 v = { f2bf(a.x), f2bf(a.y), f2bf(a.z), f2bf(a.w),
                     f2bf(c.x), f2bf(c.y), f2bf(c.z), f2bf(c.w) };
        wh[kk] = v;
    }

    // zi: batch row = bg*16 + b, cols f0 = ocw + hi*4 .. +3
    const int f0 = ocw + hi * 4;
    float4 z = zload4(zi + ((size_t)bg * 16 + b) * H_ + f0);

    // hbuf-store address bits (B-frag: kk2 = c>>5, lane2 = b | (((c>>3)&3)<<4), j0 = c&7)
    const int kk2 = f0 >> 5, j0 = f0 & 7;
    const int lane2 = b | (((f0 >> 3) & 3) << 4);

#pragma unroll 1
    for (int t = 0; t < T_; ++t) {
        const size_t zb = (size_t)t * B_ * H_;
        f32x4 acc0 = {}, acc1 = {};
        if (t > 0) {
            // ---- stage h(t-1): 32 KB from LLC -> LDS (linear copy, full MLP) ----
            const u64* hp = (const u64*)hbuf + (size_t)(((t + 1) & 1) * 8 + bg) * 4096;
            u64 sv[16];
#pragma unroll
            for (int i = 0; i < 16; ++i)
                sv[i] = AT_LD64(hp + i * 256 + tid);
#pragma unroll
            for (int i = 0; i < 16; ++i)
                lds_h[i * 256 + tid] = sv[i];
            __syncthreads();
            // ---- K-loop: pure LDS + MFMA, 2 chains ----
#pragma unroll
            for (int kk = 0; kk < 32; ++kk) {
                bf16x8 hbf = *(const bf16x8*)&lds_h[(kk * 64 + l) * 2];
                if (kk & 1)
                    acc1 = __builtin_amdgcn_mfma_f32_16x16x32_bf16(wh[kk], hbf, acc1, 0, 0, 0);
                else
                    acc0 = __builtin_amdgcn_mfma_f32_16x16x32_bf16(wh[kk], hbf, acc0, 0, 0, 0);
            }
        }
        // ---- epilogue: relu(acc + zi) -> hidden (plain f32x4) + hbuf (RMW) ----
        float v0 = fmaxf(acc0[0] + acc1[0] + z.x, 0.f);
        float v1 = fmaxf(acc0[1] + acc1[1] + z.y, 0.f);
        float v2 = fmaxf(acc0[2] + acc1[2] + z.z, 0.f);
        float v3 = fmaxf(acc0[3] + acc1[3] + z.w, 0.f);
        *(float4*)(hidden + zb + (size_t)(bg * 16 + b) * H_ + f0) =
            make_float4(v0, v1, v2, v3);
        unsigned short* hwS = hbuf + (size_t)((t & 1) * 8 + bg) * 16384;
        AT_SWP64((u64*)(hwS + (kk2 * 64 + lane2) * 8 + j0), pack4bf(v0, v1, v2, v3));

        __syncthreads();                  // vmcnt(0): RMWs executed AT the LLC
        if (tid == 0)
            AT_SWP32(&g_flags[wg * 16], (unsigned)(t + 1));  // publish (RMW)

        if (t + 1 < T_)                   // prefetch zi(t+1) under the wait
            z = zload4(zi + ((size_t)(t + 1) * B_ + bg * 16 + b) * H_ + f0);

        if (w == 0) {                     // wave 0 polls this bg's 16 producer flags
            const unsigned tgt = (unsigned)(t + 1);
            const unsigned* fp = &g_flags[(bg * 16 + (l & 15)) * 16];
            unsigned v;
            do {
                v = AT_LD32(fp);
            } while (!__all((int)(v >= tgt)));
        }
        __syncthreads();
    }
}

__global__ __launch_bounds__(256)
void copy_k(const float4* __restrict__ s, float4* __restrict__ d)
{
    int i = blockIdx.x * 256 + threadIdx.x;
    d[i] = s[i];
}

extern "C" void kernel_launch(void* const* d_in, const int* in_sizes, int n_in,
                              void* d_out, int out_size, void* d_ws, size_t ws_size,
                              hipStream_t stream)
{
    const float* x  = (const float*)d_in[0];
    const float* Wi = (const float*)d_in[1];
    const float* bi = (const float*)d_in[2];
    const float* Wh = (const float*)d_in[3];
    const float* bh = (const float*)d_in[4];
    const float* Wo = (const float*)d_in[5];
    const float* bo = (const float*)d_in[6];

    float* hidden = (float*)d_out;                       // [T][B][H]
    float* hT     = hidden + (size_t)T_ * B_ * H_;       // [B][H]
    float* y      = hT + (size_t)B_ * H_;                // [T][B][O]

    const size_t HBUF_B = (size_t)2 * B_ * H_ * sizeof(short);   // 512 KB
    const size_t ZI_B   = (size_t)T_ * B_ * H_ * sizeof(short);  // 64 MB (bf16)

    zero_flags<<<dim3(8), dim3(256), 0, stream>>>();

    short* zi;
    unsigned short* hbuf;
    if (ws_size >= HBUF_B + ZI_B) {
        hbuf = (unsigned short*)d_ws;
        zi   = (short*)((char*)d_ws + HBUF_B);
    } else {
        // zi (bf16) in y-section; hbuf in hT-section (both overwritten later)
        zi   = (short*)y;
        hbuf = (unsigned short*)hT;
    }

    gemm_bias<short><<<dim3(2048), dim3(256), 0, stream>>>(
        x, Wi, bi, bh, zi, T_ * B_, H_, DIN_);
    rnn_rec6<<<dim3(128), dim3(256), 0, stream>>>(zi, Wh, hidden, hbuf);

    // hT = hidden[T-1]
    copy_k<<<dim3(128), dim3(256), 0, stream>>>(
        (const float4*)(hidden + (size_t)(T_ - 1) * B_ * H_), (float4*)hT);

    // y = hidden @ Wo^T + bo
    gemm_bias<float><<<dim3(1024), dim3(256), 0, stream>>>(
        hidden, Wo, bo, nullptr, y, T_ * B_, DOUT_, H_);
}